// Round 6
// baseline (6555.567 us; speedup 1.0000x reference)
//
#include <hip/hip_runtime.h>
#include <hip/hip_fp16.h>

typedef unsigned int u32;

#define TSTEPS 2048
#define HID    1024
#define NDEPTH 5
#define HCB    24                   // h columns per block (last block: 16)
#define GSTAGE 43                   // ceil(1024/24)
#define NBLOCKS (NDEPTH * GSTAGE)   // 215 blocks, 1 per CU
#define HCAN   0x7c00u              // fp16 +inf: unreachable by activations
#define DCAN   0x7c007c00u
#define THS    ((size_t)TSTEPS * HID)

typedef _Float16 f16x2v __attribute__((ext_vector_type(2)));

#if defined(__has_builtin)
# if __has_builtin(__builtin_amdgcn_fdot2)
#  define HAVE_FDOT2 1
# endif
#endif

__device__ __forceinline__ float fdot2f(u32 a, u32 b, float c) {
  f16x2v x, y;
  __builtin_memcpy(&x, &a, 4);
  __builtin_memcpy(&y, &b, 4);
#ifdef HAVE_FDOT2
  return __builtin_amdgcn_fdot2(x, y, c, false);
#else
  return c + (float)x[0] * (float)y[0] + (float)x[1] * (float)y[1];
#endif
}

__device__ __forceinline__ u32 pkh(float a, float b) {
  __half2 h = __floats2half2_rn(a, b);
  u32 r;
  __builtin_memcpy(&r, &h, 4);
  return r;
}

// nonzero iff some halfword of v equals HCAN
__device__ __forceinline__ u32 canz(u32 v) {
  u32 t = v ^ DCAN;
  return ((t - 0x00010001u) & ~t) & 0x80008000u;
}

// LLC-direct 32B spin-load (2 x dwordx4); exits when no halfword is canary.
__device__ __forceinline__ void spin32(const uint4* p, uint4& a, uint4& b) {
  int tries = 0;
  for (;;) {
    uint4 ta, tb;
    asm volatile(
        "global_load_dwordx4 %0, %2, off sc0 sc1\n\t"
        "global_load_dwordx4 %1, %3, off sc0 sc1\n\t"
        "s_waitcnt vmcnt(0)"
        : "=&v"(ta), "=&v"(tb)
        : "v"(p), "v"(p + 1));
    u32 bad = canz(ta.x) | canz(ta.y) | canz(ta.z) | canz(ta.w) |
              canz(tb.x) | canz(tb.y) | canz(tb.z) | canz(tb.w);
    if (!bad) { a = ta; b = tb; return; }
    if (++tries > 3) __builtin_amdgcn_s_sleep(1);
  }
}

// 9 rows x 16 k of fdot2; g==2 rows go to slot (n_slot) within each q-quad
__device__ __forceinline__ void dots9(const u32 W[9][8], const uint4& c0,
                                      const uint4& c1, float acc[12], int n_slot) {
  u32 h[8] = {c0.x, c0.y, c0.z, c0.w, c1.x, c1.y, c1.z, c1.w};
#pragma unroll
  for (int j = 0; j < 8; ++j)
#pragma unroll
    for (int r = 0; r < 9; ++r) {
      const int q = r / 3, g = r % 3;
      const int slot = 4 * q + ((g == 2) ? n_slot : g);
      acc[slot] = fdot2f(W[r][j], h[j], acc[slot]);
    }
}

// ---------------------------------------------------------------------------
// canary fill for fp16 slabs S1..S5
// ---------------------------------------------------------------------------
__global__ __launch_bounds__(256) void fill_canary(u32* __restrict__ p, long n) {
  long i = ((long)blockIdx.x * 256 + threadIdx.x) * 4;
  const long stride = (long)gridDim.x * 256 * 4;
  uint4 c;
  c.x = DCAN; c.y = DCAN; c.z = DCAN; c.w = DCAN;
  for (; i < n; i += stride) *(uint4*)(p + i) = c;
}

// ---------------------------------------------------------------------------
// lin1: S0[t][h] = fp16( lines[t] . w1[h] + b1[h] )
// ---------------------------------------------------------------------------
__global__ __launch_bounds__(256) void lin1_kernel(
    const float* __restrict__ x, const float* __restrict__ w1,
    const float* __restrict__ b1, __half* __restrict__ X0) {
  __shared__ float lt[32][65];
  __shared__ float wt[128][65];
  const int tid = threadIdx.x;
  const int t0 = blockIdx.x * 32;
  const int h0 = blockIdx.y * 128;
  const int tt0 = (tid & 7) * 4;
  const int hh0 = (tid >> 3) * 4;
  float acc[4][4] = {};
  for (int kc = 0; kc < 512; kc += 64) {
    __syncthreads();
#pragma unroll
    for (int m = 0; m < 8; ++m) {
      int e = tid + m * 256;
      int tt = e >> 6, kk = e & 63;
      int k = kc + kk;
      int aa = k >> 5, io = k & 31;
      int d = (aa == 0) ? 0 : (aa + 1);
      int st = t0 + tt - d;
      lt[tt][kk] = (st >= 0) ? x[st * 32 + io] : 0.f;
    }
#pragma unroll
    for (int m = 0; m < 32; ++m) {
      int e = tid + m * 256;
      int hh = e >> 6, kk = e & 63;
      wt[hh][kk] = w1[(size_t)(h0 + hh) * 512 + kc + kk];
    }
    __syncthreads();
    for (int kk = 0; kk < 64; ++kk) {
      float la[4], wa[4];
#pragma unroll
      for (int i = 0; i < 4; ++i) la[i] = lt[tt0 + i][kk];
#pragma unroll
      for (int j = 0; j < 4; ++j) wa[j] = wt[hh0 + j][kk];
#pragma unroll
      for (int i = 0; i < 4; ++i)
#pragma unroll
        for (int j = 0; j < 4; ++j) acc[i][j] = fmaf(la[i], wa[j], acc[i][j]);
    }
  }
#pragma unroll
  for (int i = 0; i < 4; ++i)
#pragma unroll
    for (int j = 0; j < 4; ++j)
      X0[(size_t)(t0 + tt0 + i) * HID + h0 + hh0 + j] =
          __float2half_rn(acc[i][j] + b1[h0 + hh0 + j]);
}

// ---------------------------------------------------------------------------
// persistent GRU pipeline: 5 layers x 43 blocks, 8 waves/block.
// Wave w owns k-slice [128w,128w+128) of all 72 block rows + gates of triple w.
// Lane (a,b): jj-triple a, k in [128w+16b,+16). No __syncthreads in loop;
// cross-wave combine via LDS scoreboard + monotonic LDS counter.
// ---------------------------------------------------------------------------
__global__ __launch_bounds__(512, 2) void gru_pipe(
    const float* __restrict__ wih, const float* __restrict__ whh,
    const float* __restrict__ bih, const float* __restrict__ bhh,
    __half* __restrict__ Xh) {
  const int bid = blockIdx.x;
  const int l  = bid / GSTAGE, bs = bid % GSTAGE;
  const int tid = (int)threadIdx.x;
  const int lane = tid & 63;
  const int wv = tid >> 6;          // 0..7
  const int a  = lane >> 3;         // jj-triple owned by this lane's rows
  const int b  = lane & 7;          // k sub-slice
  const int h_base = bs * HCB;
  const int h_cnt  = (HID - h_base < HCB) ? (HID - h_base) : HCB;
  const int kb = 128 * wv + 16 * b; // this lane's k base

  const __half* xin = Xh + (size_t)l * THS;
  __half* hout      = Xh + (size_t)(l + 1) * THS;

  // ---- weights: 9 rows (triple a x gates r,z,n), 16 k each, fp16 packed ----
  u32 wA[9][8], wB[9][8];
  const size_t lw = (size_t)l * 3 * HID * HID;
#pragma unroll
  for (int r = 0; r < 9; ++r) {
    const int q = r / 3, g = r % 3;
    const int jj = 3 * a + q;
    if (jj < h_cnt) {
      const float4* pa =
          (const float4*)(wih + lw + (size_t)(g * HID + h_base + jj) * HID + kb);
      const float4* pb =
          (const float4*)(whh + lw + (size_t)(g * HID + h_base + jj) * HID + kb);
#pragma unroll
      for (int s = 0; s < 4; ++s) {
        float4 fa = pa[s], fb = pb[s];
        wA[r][2 * s]     = pkh(fa.x, fa.y);
        wA[r][2 * s + 1] = pkh(fa.z, fa.w);
        wB[r][2 * s]     = pkh(fb.x, fb.y);
        wB[r][2 * s + 1] = pkh(fb.z, fb.w);
      }
    } else {
#pragma unroll
      for (int j = 0; j < 8; ++j) { wA[r][j] = 0u; wB[r][j] = 0u; }
    }
  }

  // ---- gate-lane biases (wave wv, lanes 0-2 -> jj = h_base + 3*wv + lane) ----
  float Br = 0.f, Bz = 0.f, bin_ = 0.f, bhn_ = 0.f;
  {
    const int q = (lane < 3) ? lane : 0;
    const int jj = 3 * wv + q;
    if (lane < 3 && jj < h_cnt) {
      const float* bi = bih + (size_t)l * 3 * HID;
      const float* bh = bhh + (size_t)l * 3 * HID;
      Br   = bi[0 * HID + h_base + jj] + bh[0 * HID + h_base + jj];
      Bz   = bi[1 * HID + h_base + jj] + bh[1 * HID + h_base + jj];
      bin_ = bi[2 * HID + h_base + jj];
      bhn_ = bh[2 * HID + h_base + jj];
    }
  }

  __shared__ float4 scr[2][8][8][3];  // [phase][writer wave][triple][q-quad]
  __shared__ int cnt;
  if (tid == 0) cnt = 0;
  __syncthreads();  // prologue only

  const int fidx = 2 * (8 * wv + b);  // uint4 index of this lane's 32B fragment

  // prologue: x_0 fragment (blocking; S0 pre-filled for l==0)
  uint4 xc0, xc1;
  spin32((const uint4*)xin + fidx, xc0, xc1);

  float hprev = 0.f;

  for (int t = 0; t < TSTEPS; ++t) {
    // validate prefetched x_t (plain-cached); rare sc-bypass refetch
    {
      u32 bad = canz(xc0.x) | canz(xc0.y) | canz(xc0.z) | canz(xc0.w) |
                canz(xc1.x) | canz(xc1.y) | canz(xc1.z) | canz(xc1.w);
      if (bad) spin32((const uint4*)(xin + (size_t)t * HID) + fidx, xc0, xc1);
    }

    float acc[12];
#pragma unroll
    for (int i = 0; i < 12; ++i) acc[i] = 0.f;

    // gi dots — in the h-visibility shadow
    dots9(wA, xc0, xc1, acc, 2);

    // prefetch x_{t+1} (plain cached loads; canary-validated next iter)
    const int tn = (t + 1 < TSTEPS) ? (t + 1) : (TSTEPS - 1);
    const uint4* xp = (const uint4*)(xin + (size_t)tn * HID) + fidx;
    uint4 nx0 = xp[0], nx1 = xp[1];

    // spin on h_{t-1} fragment (coalesced: 8 lanes share each 32B chunk)
    uint4 hc0, hc1;
    if (t > 0) {
      spin32((const uint4*)(hout + (size_t)(t - 1) * HID) + fidx, hc0, hc1);
    } else {
      hc0.x = hc0.y = hc0.z = hc0.w = 0u;
      hc1 = hc0;
    }

    // gh dots
    dots9(wB, hc0, hc1, acc, 3);

    // reduce partial sums over b (lane bits 0..2)
#pragma unroll
    for (int i = 0; i < 12; ++i) {
      acc[i] += __shfl_xor(acc[i], 1);
      acc[i] += __shfl_xor(acc[i], 2);
      acc[i] += __shfl_xor(acc[i], 4);
    }

    const int p = t & 1;
    if (b == 0) {
      scr[p][wv][a][0] = make_float4(acc[0], acc[1], acc[2], acc[3]);
      scr[p][wv][a][1] = make_float4(acc[4], acc[5], acc[6], acc[7]);
      scr[p][wv][a][2] = make_float4(acc[8], acc[9], acc[10], acc[11]);
    }
    asm volatile("s_waitcnt lgkmcnt(0)" ::: "memory");
    if (lane == 0)
      __hip_atomic_fetch_add(&cnt, 1, __ATOMIC_RELAXED, __HIP_MEMORY_SCOPE_WORKGROUP);
    while (__hip_atomic_load(&cnt, __ATOMIC_ACQUIRE, __HIP_MEMORY_SCOPE_WORKGROUP) <
           8 * (t + 1)) { }

    // gates: wave wv, lanes 0-2 own jj = h_base + 3*wv + lane
    const int jjg = 3 * wv + lane;
    if (lane < 3 && jjg < h_cnt) {
      float4 s = scr[p][0][wv][lane];
#pragma unroll
      for (int w2 = 1; w2 < 8; ++w2) {
        float4 u = scr[p][w2][wv][lane];
        s.x += u.x; s.y += u.y; s.z += u.z; s.w += u.w;
      }
      float rr = 1.f / (1.f + __expf(-(s.x + Br)));
      float zz = 1.f / (1.f + __expf(-(s.y + Bz)));
      float targ = (s.z + bin_) + rr * (s.w + bhn_);
      targ = fminf(fmaxf(targ, -15.f), 15.f);
      float e2 = __expf(2.f * targ);
      float nn = (e2 - 1.f) / (e2 + 1.f);
      float hv = (1.f - zz) * nn + zz * hprev;
      hprev = hv;
      u32 hb = (u32)__half_as_ushort(__float2half_rn(hv));
      const __half* dst = hout + (size_t)t * HID + h_base + jjg;
      asm volatile("global_store_short %0, %1, off sc0 sc1" :: "v"(dst), "v"(hb));
    }

    xc0 = nx0;
    xc1 = nx1;
  }
}

// ---------------------------------------------------------------------------
// lin2: out[o,t,io] = h5[t] . w2[o*32+io] + b2   (h5 = S5, fp16)
// ---------------------------------------------------------------------------
__global__ __launch_bounds__(256) void lin2_kernel(
    const __half* __restrict__ h5, const float* __restrict__ w2,
    const float* __restrict__ b2, float* __restrict__ out) {
  __shared__ float at[64][65];
  __shared__ float bt[64][65];
  const int tid = threadIdx.x;
  const int t0 = blockIdx.x * 64;
  const int j0 = blockIdx.y * 64;
  const int tt0 = (tid & 15) * 4;
  const int jj0 = (tid >> 4) * 4;
  float acc[4][4] = {};
  for (int kc = 0; kc < 1024; kc += 64) {
    __syncthreads();
#pragma unroll
    for (int m = 0; m < 16; ++m) {
      int e = tid + m * 256;
      int tt = e >> 6, kk = e & 63;
      at[tt][kk] = __half2float(h5[(size_t)(t0 + tt) * HID + kc + kk]);
    }
#pragma unroll
    for (int m = 0; m < 16; ++m) {
      int e = tid + m * 256;
      int jj = e >> 6, kk = e & 63;
      bt[jj][kk] = w2[(size_t)(j0 + jj) * HID + kc + kk];
    }
    __syncthreads();
    for (int kk = 0; kk < 64; ++kk) {
      float la[4], wa[4];
#pragma unroll
      for (int i = 0; i < 4; ++i) la[i] = at[tt0 + i][kk];
#pragma unroll
      for (int j = 0; j < 4; ++j) wa[j] = bt[jj0 + j][kk];
#pragma unroll
      for (int i = 0; i < 4; ++i)
#pragma unroll
        for (int j = 0; j < 4; ++j) acc[i][j] = fmaf(la[i], wa[j], acc[i][j]);
    }
  }
#pragma unroll
  for (int i = 0; i < 4; ++i)
#pragma unroll
    for (int jq = 0; jq < 4; ++jq) {
      int j = j0 + jj0 + jq;
      out[(size_t)(j >> 5) * (TSTEPS * 32) + (size_t)(t0 + tt0 + i) * 32 + (j & 31)] =
          acc[i][jq] + b2[j];
    }
}

extern "C" void kernel_launch(void* const* d_in, const int* in_sizes, int n_in,
                              void* d_out, int out_size, void* d_ws, size_t ws_size,
                              hipStream_t stream) {
  const float* x   = (const float*)d_in[0];
  const float* w1  = (const float*)d_in[1];
  const float* b1  = (const float*)d_in[2];
  const float* wih = (const float*)d_in[3];
  const float* whh = (const float*)d_in[4];
  const float* bih = (const float*)d_in[5];
  const float* bhh = (const float*)d_in[6];
  const float* w2  = (const float*)d_in[7];
  const float* b2  = (const float*)d_in[8];
  float* out = (float*)d_out;

  __half* Xh = (__half*)d_ws;  // 6 fp16 slabs S0..S5 of [T][H] (24 MB)

  // arm canaries in S1..S5 (re-armed every launch/replay)
  fill_canary<<<1280, 256, 0, stream>>>((u32*)(Xh + THS),
                                        (long)NDEPTH * (long)THS / 2);
  lin1_kernel<<<dim3(64, 8), 256, 0, stream>>>(x, w1, b1, Xh);
  gru_pipe<<<NBLOCKS, 512, 0, stream>>>(wih, whh, bih, bhh, Xh);
  lin2_kernel<<<dim3(32, 4), 256, 0, stream>>>(Xh + (size_t)NDEPTH * THS,
                                               w2, b2, out);
}